// Round 1
// baseline (174.691 us; speedup 1.0000x reference)
//
#include <hip/hip_runtime.h>

// Problem constants
#define BB 8192
#define NN 8192
#define DD 256
#define GAMMA_INV_2SQ 0.0078125f        // 1/(2*8^2) = 1/128
#define EPS_C 0.001f
#define PRE_SCALE (-1.44269504f / 128.f) // -log2e/128 (folded into rsq/xsq)
#define S_COEF    (1.44269504f / 64.f)   //  log2e/64  (coef of S in exp2 arg)

typedef __attribute__((ext_vector_type(4))) float v4f;
typedef __attribute__((ext_vector_type(16))) float v16f;
typedef __attribute__((ext_vector_type(8))) int v8i;

// ---- fp8 (OCP e4m3) pack: 4 floats -> u32 (byte0=a .. byte3=d)
__device__ __forceinline__ unsigned f2fp8pk4(float a, float b, float c, float d) {
    int v = 0;
    v = __builtin_amdgcn_cvt_pk_fp8_f32(a, b, v, false);
    v = __builtin_amdgcn_cvt_pk_fp8_f32(c, d, v, true);
    return (unsigned)v;
}

// ---- async global->LDS, 16B per lane (lds base wave-uniform)
typedef const __attribute__((address_space(1))) void* gas_t;
typedef __attribute__((address_space(3))) void* las_t;
__device__ __forceinline__ void ld16(const void* g, void* l) {
    __builtin_amdgcn_global_load_lds((gas_t)g, (las_t)l, 16, 0, 0);
}

// ---- MX-scaled MFMA wrappers, scales = 1.0 (e8m0 0x7F), fmt fp8/fp8
#define SC1 0x7F7F7F7F
__device__ __forceinline__ v4f mfma16(v8i a, v8i b, v4f c) {
    return __builtin_amdgcn_mfma_scale_f32_16x16x128_f8f6f4(a, b, c, 0, 0, 0, SC1, 0, SC1);
}
__device__ __forceinline__ v16f mfma32(v8i a, v8i b, v16f c) {
    return __builtin_amdgcn_mfma_scale_f32_32x32x64_f8f6f4(a, b, c, 0, 0, 0, SC1, 0, SC1);
}

__device__ __forceinline__ v8i mk8l(long a, long b, long c, long d) {
    union { long l[4]; v8i v; } u;
    u.l[0] = a; u.l[1] = b; u.l[2] = c; u.l[3] = d;
    return u.v;
}
__device__ __forceinline__ v8i mk8i(int4 a, int4 b) {
    union { int4 i[2]; v8i v; } u;
    u.i[0] = a; u.i[1] = b;
    return u.v;
}

// ---------------- prep (256 blocks x 256): ref -> sAg (swizzled row image),
// sTg/sT2g (LINEAR transposed 64n-window images: byte[w*16384 + d*64 + n64]),
// rsq_pre (scaled). zeroM for atomic path.
__global__ __launch_bounds__(256) void prep_ref(const float* __restrict__ ref,
                                                unsigned char* __restrict__ sAg,
                                                unsigned char* __restrict__ sTg,
                                                unsigned char* __restrict__ sT2g,
                                                float* __restrict__ rsq_pre,
                                                float* __restrict__ M,
                                                int zeroM) {
    __shared__ float tile[32][257];
    __shared__ float rs[32];
    const int tid = threadIdx.x;
    const int n0 = blockIdx.x * 32;
    if (tid < 32) rs[tid] = 0.f;
    __syncthreads();
    const int r = tid >> 3, p8 = tid & 7;
    float partial = 0.f;
#pragma unroll
    for (int j = 0; j < 8; ++j) {
        const int c = p8 * 32 + j * 4;
        const float4 v = *(const float4*)(ref + (size_t)(n0 + r) * DD + c);
        partial += v.x * v.x + v.y * v.y + v.z * v.z + v.w * v.w;
        tile[r][c + 0] = v.x; tile[r][c + 1] = v.y;
        tile[r][c + 2] = v.z; tile[r][c + 3] = v.w;
    }
    atomicAdd(&rs[r], partial);
    __syncthreads();
    if (tid < 32) rsq_pre[n0 + tid] = rs[tid] * PRE_SCALE;
    // sAg image: byte[r*256 + cp*8 + j], cp=(c&16)|((c^(r&15))&15)  (unchanged)
    {
        unsigned char* dstA = sAg + (size_t)blockIdx.x * 8192 + r * 256;
#pragma unroll
        for (int c4 = 0; c4 < 4; ++c4) {
            const int c = p8 * 4 + c4;
            const float* s = &tile[r][c * 8];
            const unsigned lo = f2fp8pk4(s[0], s[1], s[2], s[3]);
            const unsigned hi = f2fp8pk4(s[4], s[5], s[6], s[7]);
            const int cp = (c & 16) | ((c ^ (r & 15)) & 15);
            *(uint2*)(dstA + cp * 8) = make_uint2(lo, hi);
        }
    }
    // sTg/sT2g: LINEAR n within 64-row window (k-order must match sW rows)
    {
        const int d = tid;
        uint2 ch1[4], ch2[4];
#pragma unroll
        for (int c = 0; c < 4; ++c) {
            float v[8], v2[8];
#pragma unroll
            for (int j = 0; j < 8; ++j) { v[j] = tile[c * 8 + j][d]; v2[j] = v[j] * v[j]; }
            ch1[c] = make_uint2(f2fp8pk4(v[0], v[1], v[2], v[3]), f2fp8pk4(v[4], v[5], v[6], v[7]));
            ch2[c] = make_uint2(f2fp8pk4(v2[0], v2[1], v2[2], v2[3]), f2fp8pk4(v2[4], v2[5], v2[6], v2[7]));
        }
        unsigned char* dT  = sTg  + (size_t)(n0 >> 6) * 16384 + (size_t)d * 64 + (n0 & 32);
        unsigned char* dT2 = sT2g + (size_t)(n0 >> 6) * 16384 + (size_t)d * 64 + (n0 & 32);
        *(uint4*)(dT)       = make_uint4(ch1[0].x, ch1[0].y, ch1[1].x, ch1[1].y);
        *(uint4*)(dT + 16)  = make_uint4(ch1[2].x, ch1[2].y, ch1[3].x, ch1[3].y);
        *(uint4*)(dT2)      = make_uint4(ch2[0].x, ch2[0].y, ch2[1].x, ch2[1].y);
        *(uint4*)(dT2 + 16) = make_uint4(ch2[2].x, ch2[2].y, ch2[3].x, ch2[3].y);
    }
    if (zeroM) {
        float4* mz = (float4*)M + (size_t)blockIdx.x * 2048;
#pragma unroll
        for (int j = 0; j < 8; ++j)
            mz[j * 256 + tid] = make_float4(0.f, 0.f, 0.f, 0.f);
    }
}

// ---------------- main fused kernel: MX-scaled fp8 MFMA (K=128 / K=64)
// grid = 1024 blocks (XCD-swizzled, b-tile 32 x n-quarter 2048), 512 threads (8 waves)
// per iteration: 64-n window. Phase B: 2x mfma16x16x128; Phase D: 2x mfma32x32x64.
// sT/sT2 go global->VGPR directly (no intra-block reuse -> no LDS staging).
// LDS: sA 2x16K | sW 2x2560 (pitch 80) | rsq 8K | wsum 512B
#define SA_OFF   0
#define SW_OFF   32768
#define SRSQ_OFF 37888
#define SWS_OFF  46080
#define SMEM_SZ  46592

template <bool ATOMIC>
__global__ __launch_bounds__(512, 4) void hland_main(
        const unsigned char* __restrict__ sAg,
        const unsigned char* __restrict__ sTg,
        const unsigned char* __restrict__ sT2g,
        const float* __restrict__ rsq_pre,
        const float* __restrict__ x_t,
        float* __restrict__ M) {        // ATOMIC: final M accum; else 4 partials
    __shared__ __align__(16) char smem[SMEM_SZ];

    const int tid = threadIdx.x;
    const int wave = tid >> 6, lane = tid & 63;
    const int quad = lane >> 4, l16 = lane & 15;
    const int l32 = lane & 31, khalf = lane >> 5;
    const int nt = wave >> 1, btB = wave & 1, dq = wave;
    // XCD swizzle: blocks on XCD j (= blk%8) share n-quarter q=j>>1
    const int q = (blockIdx.x & 7) >> 1;
    const int btile = ((blockIdx.x >> 3) << 1) | (blockIdx.x & 1);
    const int b0 = btile * 32;
    const int w0 = q * 32;              // first 64n-window of this quarter

    // ---- prologue: stage sA window 0 + rsq quarter
    const int stage_goff = wave * 1024 + (lane << 4);
    const int stage_loff = wave * 1024;
    {
        const size_t g = (size_t)w0 * 16384 + stage_goff;
        ld16(sAg + g,        smem + SA_OFF + stage_loff);
        ld16(sAg + g + 8192, smem + SA_OFF + 8192 + stage_loff);
    }
    ((float4*)(smem + SRSQ_OFF))[tid] = ((const float4*)(rsq_pre + w0 * 64))[tid];

    // ---- prologue: build x B-fragments (K=128 layout: k=(lane>>4)*32+j) + xsq
    v8i bfr0, bfr1;
    float xsqp_lane;
    {
        const float* xr = x_t + (size_t)(b0 + btB * 16 + l16) * DD + quad * 32;
        float ss = 0.f;
#pragma unroll
        for (int cc = 0; cc < 4; ++cc) {
            const float4 a = *(const float4*)(xr + cc * 8);
            const float4 b = *(const float4*)(xr + cc * 8 + 4);
            ss += a.x*a.x + a.y*a.y + a.z*a.z + a.w*a.w
                + b.x*b.x + b.y*b.y + b.z*b.z + b.w*b.w;
            bfr0[2*cc]     = (int)f2fp8pk4(a.x, a.y, a.z, a.w);
            bfr0[2*cc + 1] = (int)f2fp8pk4(b.x, b.y, b.z, b.w);
        }
#pragma unroll
        for (int cc = 0; cc < 4; ++cc) {
            const float4 a = *(const float4*)(xr + 128 + cc * 8);
            const float4 b = *(const float4*)(xr + 128 + cc * 8 + 4);
            ss += a.x*a.x + a.y*a.y + a.z*a.z + a.w*a.w
                + b.x*b.x + b.y*b.y + b.z*b.z + b.w*b.w;
            bfr1[2*cc]     = (int)f2fp8pk4(a.x, a.y, a.z, a.w);
            bfr1[2*cc + 1] = (int)f2fp8pk4(b.x, b.y, b.z, b.w);
        }
        ss += __shfl_xor(ss, 16, 64);   // sum over quads -> full 256-d row sum
        ss += __shfl_xor(ss, 32, 64);
        xsqp_lane = ss * PRE_SCALE;
    }

    v16f acc1, acc2;
#pragma unroll
    for (int i = 0; i < 16; ++i) { acc1[i] = 0.f; acc2[i] = 0.f; }
    float wsum_acc = 0.f;
    v8i fT, fT2;                        // ref^T / ref^2^T fragments (streamed)

    // per-lane base into the linear transposed images: d = dq*32 + l32
    const unsigned char* sTbase  = sTg  + (size_t)w0 * 16384
                                 + (size_t)(dq * 32 + l32) * 64 + khalf * 32;
    const unsigned char* sT2base = sT2g + (size_t)w0 * 16384
                                 + (size_t)(dq * 32 + l32) * 64 + khalf * 32;

    __syncthreads();

    for (int it = 0; it < 32; ++it) {
        // stage next sA window (double-buffered)
        if (it < 31) {
            const size_t g = (size_t)(w0 + it + 1) * 16384 + stage_goff;
            char* sl = smem + SA_OFF + ((it + 1) & 1) * 16384 + stage_loff;
            ld16(sAg + g,        sl);
            ld16(sAg + g + 8192, sl + 8192);
        }

        // ---- Phase D(it-1): acc += w(it-1) @ refT / ref2T  (K = 64 n)
        if (it > 0) {
            const char* swb = smem + SW_OFF + ((it - 1) & 1) * 2560 + l32 * 80 + khalf * 32;
            const v8i wf = mk8i(*(const int4*)swb, *(const int4*)(swb + 16));
            acc1 = mfma32(wf, fT,  acc1);
            acc2 = mfma32(wf, fT2, acc2);
        }

        // ---- stream B-fragments for window it (used by Phase D at it+1)
        {
            const unsigned char* pT  = sTbase  + (size_t)it * 16384;
            const unsigned char* pT2 = sT2base + (size_t)it * 16384;
            fT  = mk8i(*(const int4*)pT,  *(const int4*)(pT  + 16));
            fT2 = mk8i(*(const int4*)pT2, *(const int4*)(pT2 + 16));
        }

        // ---- Phase B(it): S[n][b], two chained K=128 MFMAs over d
        v4f S = (v4f){0.f, 0.f, 0.f, 0.f};
        {
            const char* saB = smem + SA_OFF + (it & 1) * 16384 + (nt * 16 + l16) * 256;
            const int cb = quad * 4;
            {
                const long a0 = *(const long*)(saB + (((cb + 0) ^ l16) & 15) * 8);
                const long a1 = *(const long*)(saB + (((cb + 1) ^ l16) & 15) * 8);
                const long a2 = *(const long*)(saB + (((cb + 2) ^ l16) & 15) * 8);
                const long a3 = *(const long*)(saB + (((cb + 3) ^ l16) & 15) * 8);
                S = mfma16(mk8l(a0, a1, a2, a3), bfr0, S);
            }
            {
                const long a0 = *(const long*)(saB + 128 + (((cb + 0) ^ l16) & 15) * 8);
                const long a1 = *(const long*)(saB + 128 + (((cb + 1) ^ l16) & 15) * 8);
                const long a2 = *(const long*)(saB + 128 + (((cb + 2) ^ l16) & 15) * 8);
                const long a3 = *(const long*)(saB + 128 + (((cb + 3) ^ l16) & 15) * 8);
                S = mfma16(mk8l(a0, a1, a2, a3), bfr1, S);
            }
        }

        // ---- Phase C(it): w = exp2(pre + S*coef); write 64*w fp8 to sW[it&1]
        {
            const float4 r4 = *(const float4*)(smem + SRSQ_OFF + it * 256 + nt * 64 + quad * 16);
            float w0v = exp2f(fmaf(S[0], S_COEF, xsqp_lane + r4.x));
            float w1v = exp2f(fmaf(S[1], S_COEF, xsqp_lane + r4.y));
            float w2v = exp2f(fmaf(S[2], S_COEF, xsqp_lane + r4.z));
            float w3v = exp2f(fmaf(S[3], S_COEF, xsqp_lane + r4.w));
            wsum_acc += w0v + w1v + w2v + w3v;
            const unsigned pk = f2fp8pk4(w0v * 64.f, w1v * 64.f, w2v * 64.f, w3v * 64.f);
            *(unsigned*)(smem + SW_OFF + (it & 1) * 2560
                         + (btB * 16 + l16) * 80 + nt * 16 + quad * 4) = pk;
        }
        __syncthreads();
    }

    // ---- final Phase D(31)
    {
        const char* swb = smem + SW_OFF + (31 & 1) * 2560 + l32 * 80 + khalf * 32;
        const v8i wf = mk8i(*(const int4*)swb, *(const int4*)(swb + 16));
        acc1 = mfma32(wf, fT,  acc1);
        acc2 = mfma32(wf, fT2, acc2);
    }

    // ---- epilogue: wsum reduce, combine M partial, store
    float v = wsum_acc;
    v += __shfl_xor(v, 16, 64);
    v += __shfl_xor(v, 32, 64);
    float* swsum = (float*)(smem + SWS_OFF);
    if (lane < 16) swsum[wave * 16 + lane] = v;
    __syncthreads();

    float* Mq = ATOMIC ? M : (M + (size_t)q * BB * DD);
    const float inv64 = 0.015625f;
    const int d = dq * 32 + l32;
#pragma unroll
    for (int rg = 0; rg < 16; ++rg) {
        const int bl = (rg & 3) + 8 * (rg >> 2) + 4 * khalf;   // 32x32 C/D row map
        const int btb = bl >> 4, row = bl & 15;
        const float wsb = swsum[btb * 16 + row] + swsum[32 + btb * 16 + row]
                        + swsum[64 + btb * 16 + row] + swsum[96 + btb * 16 + row];
        const float xv = x_t[(size_t)(b0 + bl) * DD + d];
        const float m = (acc2[rg] - 2.f * xv * acc1[rg]) * inv64 + xv * xv * wsb;
        if (ATOMIC) atomicAdd(&Mq[(size_t)(b0 + bl) * DD + d], m);
        else        Mq[(size_t)(b0 + bl) * DD + d] = m;
    }
}

// ---------------- finish (atomic path): out = 1/(W*M + eps) in place
__global__ __launch_bounds__(256) void finish_k(float* __restrict__ M,
                                                const float* __restrict__ W) {
    const int i = blockIdx.x * blockDim.x + threadIdx.x;
    const float W0 = W[0];
    float4 m = ((const float4*)M)[i];
    float4 o;
    o.x = 1.f / (W0 * m.x + EPS_C);
    o.y = 1.f / (W0 * m.y + EPS_C);
    o.z = 1.f / (W0 * m.z + EPS_C);
    o.w = 1.f / (W0 * m.w + EPS_C);
    ((float4*)M)[i] = o;
}

// ---------------- finish (partials path): out = 1/(W*(p0+p1+p2+p3) + eps)
__global__ __launch_bounds__(256) void finish_sum(const float4* __restrict__ Mp,
                                                  const float* __restrict__ W,
                                                  float4* __restrict__ out) {
    const size_t i = (size_t)blockIdx.x * blockDim.x + threadIdx.x;
    const size_t stride = (size_t)BB * DD / 4;
    const float W0 = W[0];
    const float4 a = Mp[i], b = Mp[i + stride], c = Mp[i + 2 * stride], d = Mp[i + 3 * stride];
    float4 o;
    o.x = 1.f / (W0 * (a.x + b.x + c.x + d.x) + EPS_C);
    o.y = 1.f / (W0 * (a.y + b.y + c.y + d.y) + EPS_C);
    o.z = 1.f / (W0 * (a.z + b.z + c.z + d.z) + EPS_C);
    o.w = 1.f / (W0 * (a.w + b.w + c.w + d.w) + EPS_C);
    out[i] = o;
}

// ---------------- fallback: fp32, ZERO workspace (safety net)
__global__ __launch_bounds__(256) void hland_fb(const float* __restrict__ x_t,
                                                const float* __restrict__ ref,
                                                float* __restrict__ M) {
    __shared__ float xs[8][257];
    __shared__ float rt[32][257];
    __shared__ float Sv[8][32];
    __shared__ float wv[8][32];
    __shared__ float rsq_s[32];
    __shared__ float xsq_s[8];
    const int t = threadIdx.x;
    const int b0 = blockIdx.x * 8;
    if (t < 8) xsq_s[t] = 0.f;
    __syncthreads();
    {
        const int r = t >> 5, c = (t & 31) * 8;
        const float4 a = *(const float4*)(x_t + (size_t)(b0 + r) * DD + c);
        const float4 b = *(const float4*)(x_t + (size_t)(b0 + r) * DD + c + 4);
        xs[r][c + 0] = a.x; xs[r][c + 1] = a.y; xs[r][c + 2] = a.z; xs[r][c + 3] = a.w;
        xs[r][c + 4] = b.x; xs[r][c + 5] = b.y; xs[r][c + 6] = b.z; xs[r][c + 7] = b.w;
        atomicAdd(&xsq_s[r], a.x*a.x+a.y*a.y+a.z*a.z+a.w*a.w + b.x*b.x+b.y*b.y+b.z*b.z+b.w*b.w);
    }
    __syncthreads();
    float acc2[8], acc1[8], wsum[8];
#pragma unroll
    for (int b = 0; b < 8; ++b) { acc2[b] = 0.f; acc1[b] = 0.f; wsum[b] = 0.f; }
    const int sr = t >> 3, sg = t & 7;
    for (int tile = 0; tile < NN / 32; ++tile) {
        const int n0 = tile * 32;
        Sv[t >> 5][t & 31] = 0.f;
        if (t < 32) rsq_s[t] = 0.f;
        __syncthreads();
        {
            float p = 0.f;
#pragma unroll
            for (int j = 0; j < 8; ++j) {
                const int c = sg * 32 + j * 4;
                const float4 v = *(const float4*)(ref + (size_t)(n0 + sr) * DD + c);
                rt[sr][c + 0] = v.x; rt[sr][c + 1] = v.y; rt[sr][c + 2] = v.z; rt[sr][c + 3] = v.w;
                p += v.x * v.x + v.y * v.y + v.z * v.z + v.w * v.w;
            }
            atomicAdd(&rsq_s[sr], p);
        }
        __syncthreads();
        {
            float part[8];
#pragma unroll
            for (int b = 0; b < 8; ++b) part[b] = 0.f;
            for (int jj = 0; jj < 32; ++jj) {
                const int c = sg * 32 + ((jj + sg * 4) & 31);
                const float rv = rt[sr][c];
#pragma unroll
                for (int b = 0; b < 8; ++b) part[b] += xs[b][c] * rv;
            }
#pragma unroll
            for (int b = 0; b < 8; ++b) atomicAdd(&Sv[b][sr], part[b]);
        }
        __syncthreads();
        {
            const int b = t >> 5, n = t & 31;
            const float dist = xsq_s[b] + rsq_s[n] - 2.f * Sv[b][n];
            wv[b][n] = __expf(dist * (-GAMMA_INV_2SQ));
        }
        __syncthreads();
        for (int n = 0; n < 32; ++n) {
            const float rv = rt[n][t];
            const float rv2 = rv * rv;
#pragma unroll
            for (int b = 0; b < 8; ++b) {
                const float w = wv[b][n];
                acc1[b] += w * rv; acc2[b] += w * rv2; wsum[b] += w;
            }
        }
        __syncthreads();
    }
#pragma unroll
    for (int b = 0; b < 8; ++b) {
        const float xv = xs[b][t];
        M[(size_t)(b0 + b) * DD + t] = acc2[b] - 2.f * xv * acc1[b] + xv * xv * wsum[b];
    }
}

extern "C" void kernel_launch(void* const* d_in, const int* in_sizes, int n_in,
                              void* d_out, int out_size, void* d_ws, size_t ws_size,
                              hipStream_t stream) {
    const float* x_t = (const float*)d_in[0];
    const float* ref = (const float*)d_in[1];
    const float* W   = (const float*)d_in[2];
    float* out = (float*)d_out;

    const size_t PART_SZ = (size_t)BB * DD * 4;                 // 8 MB per partial
    const size_t TILES_SZ = (size_t)6 * 1024 * 1024 + 32768;    // sAg,sTg,sT2g + rsq
    const size_t WS_A = 4 * PART_SZ + TILES_SZ;                 // ~38.03 MB
    const size_t WS_B = TILES_SZ;                               // ~6.03 MB

    if (ws_size >= WS_B) {
        const bool partials = (ws_size >= WS_A);
        char* ws = (char*)d_ws;
        float* Mp = (float*)ws;                                 // 4 partials (path A)
        char* tb = partials ? (ws + 4 * PART_SZ) : ws;
        unsigned char* sAg  = (unsigned char*)(tb);
        unsigned char* sTg  = (unsigned char*)(tb + (size_t)2 * 1024 * 1024);
        unsigned char* sT2g = (unsigned char*)(tb + (size_t)4 * 1024 * 1024);
        float* rsq = (float*)(tb + (size_t)6 * 1024 * 1024);

        prep_ref<<<256, 256, 0, stream>>>(ref, sAg, sTg, sT2g, rsq, out, partials ? 0 : 1);
        if (partials) {
            hland_main<false><<<1024, 512, 0, stream>>>(sAg, sTg, sT2g, rsq, x_t, Mp);
            finish_sum<<<(BB * DD / 4) / 256, 256, 0, stream>>>((const float4*)Mp, W, (float4*)out);
        } else {
            hland_main<true><<<1024, 512, 0, stream>>>(sAg, sTg, sT2g, rsq, x_t, out);
            finish_k<<<(BB * DD / 4) / 256, 256, 0, stream>>>(out, W);
        }
    } else {
        hland_fb<<<BB / 8, 256, 0, stream>>>(x_t, ref, out);
        finish_k<<<(BB * DD / 4) / 256, 256, 0, stream>>>(out, W);
    }
}